// Round 1
// 234.398 us; speedup vs baseline: 1.0187x; 1.0187x over previous
//
#include <hip/hip_runtime.h>

// Problem constants (fixed by reference)
#define BB 16
#define CC 256
#define HH 100
#define WW 100
#define NN 100
#define RH 40
#define RW 40
#define KK 599   // num classes

// out has BB*KK*CC = 2,453,504 floats = 613,376 float4 = 2396 blocks * 256
#define ZERO_BLOCKS 2396

// Clear the whole output with coalesced float4 stores. With N=100 boxes per
// image, at most 100 of the 599 class rows per batch are nonzero; pool_kernel
// only overwrites those, everything else stays exactly 0 (matches reference).
__global__ __launch_bounds__(256) void zero_kernel(float4* __restrict__ out)
{
    out[(size_t)blockIdx.x * 256 + threadIdx.x] = make_float4(0.f, 0.f, 0.f, 0.f);
}

// Fused: bilinear resize (100x100 -> 40x40, half-pixel) into LDS, per-box
// average pooling via direct region sum (boxes are <=5x5 cells), per-class
// scatter-mean into LDS, sparse direct write of nonzero class rows to
// out[b][k][c]. No workspace, no transpose pass.
__global__ __launch_bounds__(256) void pool_kernel(
    const float* __restrict__ feat, const float* __restrict__ boxes,
    const int* __restrict__ cls, float* __restrict__ out)
{
    __shared__ float tile[RH][RW + 1];  // +1 pad: random per-box LDS reads
    __shared__ float sums[KK];
    __shared__ float cnts[KK];

    // XCD-chunked swizzle: HW round-robins blockIdx across 8 XCDs, so blocks
    // with raw%8==x land on XCD x. Map each XCD to a contiguous chunk of the
    // logical (b,c) space so the 16 blocks writing one 64B out line
    // (consecutive c, same b,k) share one L2 -> full-line writeback instead
    // of 8-16x partial-line amplification.
    const int raw = blockIdx.x;
    const int L = (raw & 7) * (BB * CC / 8) + (raw >> 3);  // bijective, 4096 blocks
    const int b = L >> 8;        // / 256
    const int c = L & 255;
    const int tid = threadIdx.x;

    // Early box/class loads (threads 0..99): issue before the resize phase so
    // their latency hides under the tile build; consumed after the barrier.
    float bx0 = 0.f, bx1 = 0.f, bx2 = 0.f, bx3 = 0.f;
    int myk = 0;
    if (tid < NN) {
        const float* bp = boxes + (size_t)(b * NN + tid) * 4;
        bx0 = bp[0]; bx1 = bp[1]; bx2 = bp[2]; bx3 = bp[3];
        myk = cls[b * NN + tid];
    }

    const float* __restrict__ src = feat + (size_t)(b * CC + c) * (HH * WW);

    // ---- bilinear resize into LDS ----
    // src coord = (o+0.5)*2.5 - 0.5 = 2.5*o + 0.75 ; always interior.
    // i0 = (5o+1)>>1 ; frac = 0.75 (o even) / 0.25 (o odd)
    for (int idx = tid; idx < RH * RW; idx += 256) {
        int oy = idx / RW;
        int ox = idx - oy * RW;
        int iy0 = (5 * oy + 1) >> 1;
        int ix0 = (5 * ox + 1) >> 1;
        float fy = (oy & 1) ? 0.25f : 0.75f;
        float fx = (ox & 1) ? 0.25f : 0.75f;
        const float* r0 = src + iy0 * WW + ix0;
        float v00 = r0[0], v01 = r0[1];
        float v10 = r0[WW], v11 = r0[WW + 1];
        float top = (1.0f - fx) * v00 + fx * v01;
        float bot = (1.0f - fx) * v10 + fx * v11;
        tile[oy][ox] = (1.0f - fy) * top + fy * bot;
    }

    for (int k = tid; k < KK; k += 256) {
        sums[k] = 0.0f;
        cnts[k] = 0.0f;
    }
    __syncthreads();

    // ---- per-box pooling + class scatter (threads 0..99) ----
    if (tid < NN) {
        const float sc = 0.0390625f;  // 40/1024 = 5/128, exact
        // rintf -> v_rndne_f32: round half to even, matches jnp.round
        int x1 = (int)rintf(bx0 * sc);
        int y1 = (int)rintf(bx1 * sc);
        int x2 = (int)rintf(bx2 * sc);
        int y2 = (int)rintf(bx3 * sc);
        x1 = max(x1, 0); y1 = max(y1, 0);
        x2 = min(x2, RW); y2 = min(y2, RH);
        if (x1 < x2 && y1 < y2) {
            float s = 0.0f;
            for (int y = y1; y < y2; ++y)
                for (int x = x1; x < x2; ++x)
                    s += tile[y][x];
            float area = (float)((y2 - y1) * (x2 - x1));
            atomicAdd(&sums[myk], s / area);
            atomicAdd(&cnts[myk], 1.0f);
        }
    }
    __syncthreads();

    // ---- sparse write of nonzero class means: out[b][k][c] ----
    // <=100 of 599 iterations actually store (predicated, 4B each). The lines
    // are assembled in this XCD's L2 thanks to the chunked swizzle.
    float* o = out + (size_t)b * KK * CC + c;
    for (int k = tid; k < KK; k += 256) {
        float cn = cnts[k];
        if (cn > 0.0f) o[(size_t)k * CC] = sums[k] / cn;
    }
}

extern "C" void kernel_launch(void* const* d_in, const int* in_sizes, int n_in,
                              void* d_out, int out_size, void* d_ws, size_t ws_size,
                              hipStream_t stream) {
    (void)d_ws; (void)ws_size; (void)in_sizes; (void)n_in; (void)out_size;
    const float* feat  = (const float*)d_in[0];
    const float* boxes = (const float*)d_in[1];
    const int*   cls   = (const int*)d_in[2];
    float* out = (float*)d_out;

    zero_kernel<<<ZERO_BLOCKS, 256, 0, stream>>>((float4*)out);
    pool_kernel<<<BB * CC, 256, 0, stream>>>(feat, boxes, cls, out);
}